// Round 9
// baseline (213.844 us; speedup 1.0000x reference)
//
#include <hip/hip_runtime.h>
#include <cmath>
#include <stdint.h>

#define NPTS   86016
#define NCB    1024          // coarse bins per level (f32 score bits >> 20)
#define K_TOP  1000
#define NOUT   3000
#define NWORDS 47            // ceil(3000/64)
#define NTILE  47
#define NTILES (NTILE * (NTILE + 1) / 2)   // 1128
#define ECAP   8192
#define FCAP   1024
#define SPPB   64            // score points per block (1344 blocks)

// ---- workspace layout (bytes): chist + fine hist + cnt contiguous (one tiny memset) ----
#define CH_OFF     0
#define FINE_OFF   (NCB * 3 * 4)                // 12,288 : 3 x 256 fine bins
#define CNT_OFF    (FINE_OFF + 3 * 256 * 4)     // 15,360
// cnt[0..2]=comb_cnt [3..5]=above_cnt [9..11]=scan-done [12]=edge_cnt [13]=flag_cnt
// cnt[14]=score-done [15]=select-done [16]=edge-done
#define MEMSET_BYTES (CNT_OFF + 128)            // 15,488 total
#define KEYS_OFF   (CNT_OFF + 128)
#define LAB_OFF    (KEYS_OFF + NPTS * 8)
#define COMB_OFF   (LAB_OFF + NPTS * 4)         // 3 x 65536 combined (cb>=chunk) keys
#define SURV_OFF   (COMB_OFF + 3 * 65536 * 8)
#define EDGE_OFF   (SURV_OFF + NOUT * 8 + 64)
#define FLAG_OFF   (EDGE_OFF + ECAP * 4)

// stepwise-f32 sigmoid: CR f32 exp, then IEEE f32 add + div (matches numpy per-op chain)
__device__ __forceinline__ float sig_f32_stepwise(float x) {
    float e = (float)exp(-(double)x);   // correctly-rounded f32 exp(-x)
    return 1.0f / (1.0f + e);           // f32 add (CR), f32 div (CR)
}

__device__ __forceinline__ void locate(int g, int& lv, int& p, int& HW) {
    if (g < 65536)      { lv = 0; p = g;         HW = 65536; }
    else if (g < 81920) { lv = 1; p = g - 65536; HW = 16384; }
    else                { lv = 2; p = g - 81920; HW = 4096;  }
}

// ---------------- kernel 1: fused score + last-block tie cleanup ----------------------
__global__ __launch_bounds__(256) void score_kernel(
        const float* __restrict__ cls0, const float* __restrict__ cls1,
        const float* __restrict__ cls2,
        const float* __restrict__ ctn0, const float* __restrict__ ctn1,
        const float* __restrict__ ctn2,
        unsigned long long* __restrict__ keys, int* __restrict__ labels,
        int* __restrict__ chist,
        int* __restrict__ cnt, unsigned* __restrict__ flags) {
    __shared__ float pm[5 * SPPB], pv[5 * SPPB];
    __shared__ int pidx[5 * SPPB];
    __shared__ int lch[NCB];                   // block-local coarse hist (block = one level)
    __shared__ int doClean;
    const int tid = threadIdx.x;
    const int base = blockIdx.x * SPPB;
    for (int i = tid; i < NCB; i += 256) lch[i] = 0;
    for (int it = tid; it < 5 * SPPB; it += 256) {
        int c = it / SPPB, pt = it - c * SPPB;
        int g = base + pt, lv, p, HW;
        locate(g, lv, p, HW);
        const float* cls = (lv == 0) ? cls0 : ((lv == 1) ? cls1 : cls2);
        const float* bp = cls + (size_t)c * 16 * HW + p;
        float x[16];
#pragma unroll
        for (int cc = 0; cc < 16; cc++) x[cc] = bp[(size_t)cc * HW];   // independent loads (MLP)
        float m = -INFINITY, v = -INFINITY; int idx = 0;
#pragma unroll
        for (int cc = 0; cc < 16; cc++)
            if (x[cc] > m) { v = m; m = x[cc]; idx = c * 16 + cc; }    // first-occurrence
        pm[it] = m; pv[it] = v; pidx[it] = idx;
    }
    __syncthreads();
    if (tid < SPPB) {
        int g = base + tid, lv, p, HW;
        locate(g, lv, p, HW);
        const float* ctn = (lv == 0) ? ctn0 : ((lv == 1) ? ctn1 : ctn2);
        float m = -INFINITY, v = -INFINITY; int idx = 0;
#pragma unroll
        for (int k = 0; k < 5; k++) {
            float bm = pm[k * SPPB + tid];
            float bv = pv[k * SPPB + tid];
            int bidx = pidx[k * SPPB + tid];
            if (bm > m) { v = fmaxf(m, bv); m = bm; idx = bidx; }
        }
        // joint = sqrt(sig(cls)*sig(ctn)) weakly monotone in cls -> max joint = joint(m)
        float sc = sig_f32_stepwise(ctn[p]);
        float sM = sig_f32_stepwise(m);
        float jm = __fsqrt_rn(sM * sc);
        float sV = sig_f32_stepwise(v);
        float jv = __fsqrt_rn(sV * sc);
        if (jv == jm) {                        // earlier-index label tie possible
            int f = atomicAdd(&cnt[13], 1);
            if (f < FCAP) flags[f] = (unsigned)g;
        }
        unsigned int bits = __float_as_uint(jm);
        keys[g] = ((unsigned long long)bits << 32) | (0xFFFFFFFFu - (unsigned)g);
        labels[g] = idx;
        atomicAdd(&lch[(int)(bits >> 20)], 1);                // coarse -> LDS
    }
    __syncthreads();
    // flush aggregated coarse bins: <=1 global atomic per bin per block
    int lv0, p0, HW0; locate(base, lv0, p0, HW0);             // whole block is in level lv0
    for (int i = tid; i < NCB; i += 256) {
        int v = lch[i];
        if (v) atomicAdd(&chist[lv0 * NCB + i], v);
    }
    // ---- last-block election: run tie cleanup (all flags complete by then) ----
    __syncthreads();                            // drain this block's stores/atomics
    if (tid == 0) {
        __threadfence();                        // release
        int prev = atomicAdd(&cnt[14], 1);
        int dc = (prev == (int)gridDim.x - 1);
        if (dc) __threadfence();                // acquire
        doClean = dc;
    }
    __syncthreads();
    if (doClean) {
        int nf = cnt[13]; if (nf > FCAP) nf = FCAP;
        int wave = tid >> 6, lane = tid & 63;
        for (int f = wave; f < nf; f += 4) {    // 4 waves in this 256-thread block
            int g = (int)flags[f], lv, p, HW;
            locate(g, lv, p, HW);
            const float* cls = (lv == 0) ? cls0 : ((lv == 1) ? cls1 : cls2);
            const float* ctn = (lv == 0) ? ctn0 : ((lv == 1) ? ctn1 : ctn2);
            float sc = sig_f32_stepwise(ctn[p]);
            float bestv = -1.0f; int besti = 127;
            {
                float s = sig_f32_stepwise(cls[(size_t)lane * HW + p]);
                float sj = __fsqrt_rn(s * sc);
                bestv = sj; besti = lane;
            }
            if (lane < 16) {
                int c2 = lane + 64;
                float s = sig_f32_stepwise(cls[(size_t)c2 * HW + p]);
                float sj = __fsqrt_rn(s * sc);
                if (sj > bestv) { bestv = sj; besti = c2; }   // tie keeps smaller idx
            }
            for (int off = 32; off; off >>= 1) {
                float ov = __shfl_xor(bestv, off, 64);
                int   oi = __shfl_xor(besti, off, 64);
                if (ov > bestv || (ov == bestv && oi < besti)) { bestv = ov; besti = oi; }
            }
            if (lane == 0) labels[g] = besti;
        }
    }
}

// ---------------- kernel 2: scan + per-level last-block select + last-select merge ----
// 84 blocks. Scan phase = round-8 scan v2 (block-aggregated appends). The last block
// to finish each level (done-counter) runs that level's select; the 3rd select to
// finish runs merge+emit. Election via device-scope atomics + release/acquire fences
// (pattern validated rounds 2/3). No spins.
__global__ __launch_bounds__(1024) void scansel_kernel(
        const unsigned long long* __restrict__ keys,
        const int* __restrict__ chist,
        int* __restrict__ cnt, int* __restrict__ fineg,
        unsigned long long* __restrict__ comb,
        unsigned long long* __restrict__ surv,
        const int* __restrict__ labels,
        const float* __restrict__ reg0, const float* __restrict__ reg1,
        const float* __restrict__ reg2,
        const float* __restrict__ scales,
        float* __restrict__ out) {
    const int bid = blockIdx.x, tid = threadIdx.x;
    const int lane = tid & 63, wv = tid >> 6;
    const unsigned long long lmlt = (1ULL << lane) - 1;
    int lv, off, nblk_lv;
    if (bid < 64)      { lv = 0; off = bid << 10;        nblk_lv = 64; }
    else if (bid < 80) { lv = 1; off = (bid - 64) << 10; nblk_lv = 16; }
    else               { lv = 2; off = (bid - 80) << 10; nblk_lv = 4;  }
    const int base = (lv == 0) ? 0 : ((lv == 1) ? 65536 : 81920);

    __shared__ int wtot[16], wsuf[16];
    __shared__ int s_chunk;
    __shared__ int lcnt, labove, lbase;
    __shared__ int doSel, doMerge;
    __shared__ int sBf, sSure, sCand;
    __shared__ union {
        unsigned long long buf[1024];                                     // scan
        struct { unsigned long long sel[1024], cbuf[1024]; } se;          // select
        struct { unsigned long long L[3][1024], s[NOUT]; } mg;            // merge (~48KB)
    } u;

    if (tid == 0) { lcnt = 0; labove = 0; doMerge = 0; }
    // issue my key load early; it resolves under the chist scan
    unsigned long long key = keys[base + off + tid];

    // coarse suffix scan (shuffle-based) -> chunk
    {
        int s = chist[lv * NCB + tid];
#pragma unroll
        for (int o = 1; o <= 32; o <<= 1) {
            int t = __shfl_down(s, o, 64);
            if (lane + o < 64) s += t;
        }
        if (lane == 0) wtot[wv] = s;
        __syncthreads();
        if (tid < 16) {
            int t = wtot[tid];
#pragma unroll
            for (int o = 1; o <= 8; o <<= 1) {
                int q = __shfl_down(t, o, 64);
                if (tid + o < 16) t += q;
            }
            wsuf[tid] = t;
        }
        __syncthreads();
        int offW = (wv < 15) ? wsuf[wv + 1] : 0;
        int part_i = s + offW;
        int s1 = __shfl_down(s, 1, 64);
        int part_n = (lane < 63) ? (s1 + offW) : offW;
        if (part_i >= K_TOP && part_n < K_TOP) s_chunk = tid;
    }
    __syncthreads();
    const int chunk = s_chunk;

    // classify into LDS buf (block-aggregated), fine hist for cb==chunk
    {
        int cb = (int)(key >> 52);             // coarse bin (f32 bits >> 20)
        bool keep = cb >= chunk;
        unsigned long long mK = __ballot(keep);
        if (mK) {
            int ldr = __ffsll((long long)mK) - 1;
            int bk;
            if (lane == ldr) bk = atomicAdd(&lcnt, __popcll(mK));   // LDS atomic (cheap)
            bk = __shfl(bk, ldr, 64);
            if (keep) u.buf[bk + __popcll(mK & lmlt)] = key;
        }
        unsigned long long mS = __ballot(cb > chunk);
        if (lane == 0 && mS) atomicAdd(&labove, __popcll(mS));      // LDS atomic
        if (cb == chunk)
            atomicAdd(&fineg[lv * 256 + ((int)(key >> 44) & 255)], 1);
    }
    __syncthreads();
    if (tid == 0) {
        lbase = atomicAdd(&cnt[0 + lv], lcnt);                      // 84 global atomics
        if (labove) atomicAdd(&cnt[3 + lv], labove);
    }
    __syncthreads();
    if (tid < lcnt) comb[(size_t)lv * 65536 + lbase + tid] = u.buf[tid];   // coalesced

    // ---- per-level last-block election -> select ----
    __syncthreads();                            // drain comb stores
    if (tid == 0) {
        __threadfence();                        // release my writes
        int prev = atomicAdd(&cnt[9 + lv], 1);
        int ds = (prev == nblk_lv - 1);
        if (ds) __threadfence();                // acquire others' writes
        doSel = ds;
    }
    __syncthreads();
    if (doSel) {
        const int n     = cnt[0 + lv];          // combined (cb>=chunk) count
        const int above = cnt[3 + lv];          // # keys with cb > chunk (<= 999)
        if (tid == 0) { sSure = 0; sCand = 0; }
        // fine suffix scan (shuffle-based, 4 waves) -> Bf
        {
            int fs = (tid < 256) ? fineg[lv * 256 + tid] : 0;
#pragma unroll
            for (int o = 1; o <= 32; o <<= 1) {
                int t = __shfl_down(fs, o, 64);
                if (lane + o < 64) fs += t;
            }
            if (tid < 256 && lane == 0) wtot[wv] = fs;   // wv in 0..3
            __syncthreads();
            if (tid < 4) {
                int t = wtot[tid];
#pragma unroll
                for (int o = 1; o <= 2; o <<= 1) {
                    int q = __shfl_down(t, o, 64);
                    if (tid + o < 4) t += q;
                }
                wsuf[tid] = t;
            }
            __syncthreads();
            if (tid < 256) {
                int offW = (wv < 3) ? wsuf[wv + 1] : 0;
                int ge = above + fs + offW;
                int fs1 = __shfl_down(fs, 1, 64);
                int genxt = above + ((lane < 63) ? (fs1 + offW) : offW);
                if (ge >= K_TOP && genxt < K_TOP) sBf = tid;
            }
        }
        __syncthreads();
        const int Bf = sBf;

        // combined-list re-scan (~n/1024 sweeps, n ~ 3.5K)
        for (int i0 = tid; ; i0 += 1024) {
            bool any = (i0 - tid) < n;          // uniform per sweep
            if (!any) break;
            bool valid = i0 < n;
            unsigned long long k2 = valid ? comb[(size_t)lv * 65536 + i0] : 0ULL;
            int cb = (int)(k2 >> 52);
            int fb = (int)(k2 >> 44) & 255;
            bool pS = valid && (cb > chunk || fb > Bf);
            bool pC = valid && (cb == chunk && fb == Bf);
            unsigned long long mS = __ballot(pS);
            if (mS) {
                int ldr = __ffsll((long long)mS) - 1;
                int bk;
                if (lane == ldr) bk = atomicAdd(&sSure, __popcll(mS));
                bk = __shfl(bk, ldr, 64);
                if (pS) u.se.sel[bk + __popcll(mS & lmlt)] = k2;   // total == Ca <= 999
            }
            unsigned long long mC = __ballot(pC);
            if (mC) {
                int ldr = __ffsll((long long)mC) - 1;
                int bk;
                if (lane == ldr) bk = atomicAdd(&sCand, __popcll(mC));
                bk = __shfl(bk, ldr, 64);
                if (pC) {
                    int pos = bk + __popcll(mC & lmlt);
                    if (pos < 1024) u.se.cbuf[pos] = k2;           // clamp (~tens realistic)
                }
            }
        }
        __syncthreads();

        // O(n) rank-sort (LDS broadcast reads, unique keys), 4-acc ILP, then concat
        const int nS = sSure;                   // == Ca <= 999
        int nC = sCand; if (nC > 1024) nC = 1024;
        unsigned long long myS = (tid < nS) ? u.se.sel[tid] : 0ULL;
        unsigned long long myC = (tid < nC) ? u.se.cbuf[tid] : 0ULL;
        int a0 = 0, a1 = 0, a2 = 0, a3 = 0;
        int i = 0;
        for (; i + 4 <= nS; i += 4) {
            a0 += (u.se.sel[i] > myS); a1 += (u.se.sel[i + 1] > myS);
            a2 += (u.se.sel[i + 2] > myS); a3 += (u.se.sel[i + 3] > myS);
        }
        for (; i < nS; i++) a0 += (u.se.sel[i] > myS);
        int rS = a0 + a1 + a2 + a3;
        int b0 = 0, b1 = 0, b2 = 0, b3 = 0;
        i = 0;
        for (; i + 4 <= nC; i += 4) {
            b0 += (u.se.cbuf[i] > myC); b1 += (u.se.cbuf[i + 1] > myC);
            b2 += (u.se.cbuf[i + 2] > myC); b3 += (u.se.cbuf[i + 3] > myC);
        }
        for (; i < nC; i++) b0 += (u.se.cbuf[i] > myC);
        int rC = b0 + b1 + b2 + b3;
        __syncthreads();                         // all reads done
        if (tid < nS) u.se.sel[rS] = myS;
        if (tid < nC) u.se.cbuf[rC] = myC;
        __syncthreads();
        // sure keys strictly > cand keys (higher fine/coarse bin) -> concat fully sorted
        if (tid < K_TOP)
            surv[lv * K_TOP + tid] = (tid < nS) ? u.se.sel[tid] : u.se.cbuf[tid - nS];

        // ---- select-done election -> merge (3rd finisher) ----
        __syncthreads();                         // drain surv stores
        if (tid == 0) {
            __threadfence();                     // release surv
            int prev = atomicAdd(&cnt[15], 1);
            int dm = (prev == 2);
            if (dm) __threadfence();             // acquire other levels' surv
            doMerge = dm;
        }
    }
    __syncthreads();
    if (doMerge) {
        // 3-way merge by ranking + emit (1024 threads)
#pragma unroll
        for (int lv2 = 0; lv2 < 3; lv2++)
            u.mg.L[lv2][tid] = (tid < K_TOP) ? surv[lv2 * K_TOP + tid] : 0ULL;
        __syncthreads();
        for (int e = tid; e < NOUT; e += 1024) {
            int a = e / K_TOP, i = e - a * K_TOP;
            unsigned long long k2 = u.mg.L[a][i];
            int rank = i;
#pragma unroll
            for (int b = 0; b < 3; b++) {
                if (b == a) continue;
                int lo = 0, hi = K_TOP;
                while (lo < hi) {
                    int mid = (lo + hi) >> 1;
                    if (u.mg.L[b][mid] > k2) lo = mid + 1; else hi = mid;
                }
                rank += lo;
            }
            u.mg.s[rank] = k2;    // keys unique -> bijective
        }
        __syncthreads();
        for (int r = tid; r < NOUT; r += 1024) {
            unsigned long long k2 = u.mg.s[r];
            unsigned int bits = (unsigned)(k2 >> 32);
            float score = __uint_as_float(bits);
            unsigned int g = 0xFFFFFFFFu - (unsigned)(k2 & 0xFFFFFFFFULL);
            int lv2, p;
            if (g < 65536u)      { lv2 = 0; p = (int)g; }
            else if (g < 81920u) { lv2 = 1; p = (int)g - 65536; }
            else                 { lv2 = 2; p = (int)g - 81920; }
            const float* rp = (lv2 == 0) ? reg0 : ((lv2 == 1) ? reg1 : reg2);
            int HW = (lv2 == 0) ? 65536 : ((lv2 == 1) ? 16384 : 4096);
            int W = 256 >> lv2;
            float strideF = (float)(8 << lv2);
            float scale = scales[lv2];
            int x = p & (W - 1);
            int y = p >> (8 - lv2);
            float r0 = fmaxf(0.0f, rp[0 * HW + p] * scale) * strideF;
            float r1 = fmaxf(0.0f, rp[1 * HW + p] * scale) * strideF;
            float r2 = fmaxf(0.0f, rp[2 * HW + p] * scale) * strideF;
            float r3 = fmaxf(0.0f, rp[3 * HW + p] * scale) * strideF;
            float ax = ((float)x + 0.5f) * strideF;
            float ay = ((float)y + 0.5f) * strideF;
            out[r * 4 + 0] = ax - r0;
            out[r * 4 + 1] = ay - r1;
            out[r * 4 + 2] = ax + r2;
            out[r * 4 + 3] = ay + r3;
            out[12000 + r] = score;
            out[15000 + r] = (float)labels[g];
        }
    }
}

// ---------------- kernel 3: tiled edge extraction + last-block sparse NMS ------------
__global__ __launch_bounds__(256) void edgenms_kernel(
        float* __restrict__ out,
        unsigned* __restrict__ edges_g,
        int* __restrict__ cnt) {
    __shared__ union {
        struct { float x1[128], y1[128], x2[128], y2[128]; } eg;
        struct { unsigned ed[ECAP]; unsigned long long supLds[NWORDS]; } nm;  // 33 KB
    } u;
    __shared__ int doNms;
    int t = blockIdx.x, tid = threadIdx.x;
    int ta = 0, rem = t;
    while (rem >= NTILE - ta) { rem -= NTILE - ta; ta++; }
    int tb = ta + rem;                         // ta <= tb
    if (tid < 64) {
        int gi = ta * 64 + tid;
        if (gi < NOUT) {
            float4 b = ((const float4*)out)[gi];
            u.eg.x1[tid] = b.x; u.eg.y1[tid] = b.y; u.eg.x2[tid] = b.z; u.eg.y2[tid] = b.w;
        }
    } else if (tid < 128) {
        int gj = tb * 64 + (tid - 64);
        if (gj < NOUT) {
            float4 b = ((const float4*)out)[gj];
            u.eg.x1[tid] = b.x; u.eg.y1[tid] = b.y; u.eg.x2[tid] = b.z; u.eg.y2[tid] = b.w;
        }
    }
    __syncthreads();
#pragma unroll
    for (int q = 0; q < 16; q++) {
        int idx = q * 256 + tid;
        int ii = idx >> 6, jj = idx & 63;
        int i = ta * 64 + ii, j = tb * 64 + jj;
        if (i < j && j < NOUT) {
            float ai = (u.eg.x2[ii] - u.eg.x1[ii]) * (u.eg.y2[ii] - u.eg.y1[ii]);
            float aj = (u.eg.x2[64 + jj] - u.eg.x1[64 + jj]) * (u.eg.y2[64 + jj] - u.eg.y1[64 + jj]);
            float xx1 = fmaxf(u.eg.x1[ii], u.eg.x1[64 + jj]), yy1 = fmaxf(u.eg.y1[ii], u.eg.y1[64 + jj]);
            float xx2 = fminf(u.eg.x2[ii], u.eg.x2[64 + jj]), yy2 = fminf(u.eg.y2[ii], u.eg.y2[64 + jj]);
            float ww = fmaxf(1e-10f, xx2 - xx1);
            float hh = fmaxf(1e-10f, yy2 - yy1);
            float inter = ww * hh;
            float iou = inter / (((ai + aj) - inter) + 1e-14f);
            if ((double)iou > 0.6) {
                int e = atomicAdd(&cnt[12], 1);
                if (e < ECAP) edges_g[e] = ((unsigned)i << 12) | (unsigned)j;
            }
        }
    }
    // ---- last-block election: run sparse NMS (edges complete by then) ----
    __syncthreads();                            // drain edge stores/atomics
    if (tid == 0) {
        __threadfence();                        // release
        int prev = atomicAdd(&cnt[16], 1);
        int dn = (prev == (int)gridDim.x - 1);
        if (dn) __threadfence();                // acquire
        doNms = dn;
    }
    __syncthreads();
    if (doNms) {
        int E = cnt[12]; if (E > ECAP) E = ECAP;
        int m = 1; while (m < E) m <<= 1;
        for (int q = tid; q < m; q += 256) u.nm.ed[q] = (q < E) ? edges_g[q] : 0xFFFFFFFFu;
        __syncthreads();
        for (int k = 2; k <= m; k <<= 1)
            for (int j = k >> 1; j > 0; j >>= 1) {
                for (int q = tid; q < m; q += 256) {
                    int l = q ^ j;
                    if (l > q) {
                        unsigned a = u.nm.ed[q], b = u.nm.ed[l];
                        if (((q & k) == 0) ? (a > b) : (a < b)) { u.nm.ed[q] = b; u.nm.ed[l] = a; }
                    }
                }
                __syncthreads();
            }
        if (tid < 64) {
            int lane = tid;
            unsigned long long supW = 0ULL;
            int ep = 0;
            for (int c = 0; c < NWORDS; c++) {
                unsigned long long cw = __shfl(supW, c, 64);   // complete: sources < c*64 final
                int hi = (c + 1) * 64;
                while (ep < E) {
                    unsigned kk = u.nm.ed[ep];
                    int i = (int)(kk >> 12);
                    if (i >= hi) break;
                    int j = (int)(kk & 4095);
                    if (!((cw >> (i & 63)) & 1ULL)) {          // source kept -> suppress target
                        if ((j >> 6) == c) cw |= 1ULL << (j & 63);
                        else if (lane == (j >> 6)) supW |= 1ULL << (j & 63);
                    }
                    ep++;
                }
                if (lane == c) supW = cw;
            }
            if (lane < NWORDS) u.nm.supLds[lane] = supW;
        }
        __syncthreads();
        for (int jj = tid; jj < NOUT; jj += 256) {
            bool s = (u.nm.supLds[jj >> 6] >> (jj & 63)) & 1ULL;
            float scv = out[12000 + jj];
            out[18000 + jj] = (!s && ((double)scv > 0.05)) ? 1.0f : 0.0f;
        }
    }
}

extern "C" void kernel_launch(void* const* d_in, const int* in_sizes, int n_in,
                              void* d_out, int out_size, void* d_ws, size_t ws_size,
                              hipStream_t stream) {
    const float* cls0 = (const float*)d_in[0];
    const float* reg0 = (const float*)d_in[1];
    const float* ctn0 = (const float*)d_in[2];
    const float* cls1 = (const float*)d_in[3];
    const float* reg1 = (const float*)d_in[4];
    const float* ctn1 = (const float*)d_in[5];
    const float* cls2 = (const float*)d_in[6];
    const float* reg2 = (const float*)d_in[7];
    const float* ctn2 = (const float*)d_in[8];
    const float* scales = (const float*)d_in[9];

    char* ws = (char*)d_ws;
    int* chist = (int*)(ws + CH_OFF);
    int* fineg = (int*)(ws + FINE_OFF);
    int* cnt  = (int*)(ws + CNT_OFF);
    unsigned long long* keys = (unsigned long long*)(ws + KEYS_OFF);
    int* labels = (int*)(ws + LAB_OFF);
    unsigned long long* comb = (unsigned long long*)(ws + COMB_OFF);
    unsigned long long* surv = (unsigned long long*)(ws + SURV_OFF);
    unsigned* edges = (unsigned*)(ws + EDGE_OFF);
    unsigned* flags = (unsigned*)(ws + FLAG_OFF);
    float* out = (float*)d_out;

    // tiny memset: coarse hist + fine hist + counters (15.5 KB)
    hipMemsetAsync(ws, 0, MEMSET_BYTES, stream);

    score_kernel<<<NPTS / SPPB, 256, 0, stream>>>(cls0, cls1, cls2, ctn0, ctn1, ctn2,
                                                  keys, labels, chist, cnt, flags);
    scansel_kernel<<<84, 1024, 0, stream>>>(keys, chist, cnt, fineg, comb, surv,
                                            labels, reg0, reg1, reg2, scales, out);
    edgenms_kernel<<<NTILES, 256, 0, stream>>>(out, edges, cnt);
}

// Round 10
// 168.576 us; speedup vs baseline: 1.2685x; 1.2685x over previous
//
#include <hip/hip_runtime.h>
#include <cmath>
#include <stdint.h>

#define NPTS   86016
#define NCB    1024          // coarse bins per level (f32 score bits >> 20)
#define K_TOP  1000
#define NOUT   3000
#define NWORDS 47            // ceil(3000/64)
#define NTILE  47
#define ECAP   8192
#define FCAP   1024
#define SPPB   64            // score points per block (1344 blocks)

// ---- workspace layout (bytes): chist + fine hist + cnt contiguous (one tiny memset) ----
#define CH_OFF     0
#define FINE_OFF   (NCB * 3 * 4)                // 12,288 : 3 x 256 fine bins
#define CNT_OFF    (FINE_OFF + 3 * 256 * 4)     // 15,360
// cnt[0..2]=comb_cnt [3..5]=above_cnt [6..8]=chunk [12]=edge_cnt [13]=flag_cnt
#define MEMSET_BYTES (CNT_OFF + 64)             // 15,424 total
#define KEYS_OFF   (CNT_OFF + 64)
#define LAB_OFF    (KEYS_OFF + NPTS * 8)
#define COMB_OFF   (LAB_OFF + NPTS * 4)         // 3 x 65536 combined (cb>=chunk) keys
#define SURV_OFF   (COMB_OFF + 3 * 65536 * 8)
#define EDGE_OFF   (SURV_OFF + NOUT * 8 + 64)
#define FLAG_OFF   (EDGE_OFF + ECAP * 4)

// stepwise-f32 sigmoid: CR f32 exp, then IEEE f32 add + div (matches numpy per-op chain)
__device__ __forceinline__ float sig_f32_stepwise(float x) {
    float e = (float)exp(-(double)x);   // correctly-rounded f32 exp(-x)
    return 1.0f / (1.0f + e);           // f32 add (CR), f32 div (CR)
}

__device__ __forceinline__ void locate(int g, int& lv, int& p, int& HW) {
    if (g < 65536)      { lv = 0; p = g;         HW = 65536; }
    else if (g < 81920) { lv = 1; p = g - 65536; HW = 16384; }
    else                { lv = 2; p = g - 81920; HW = 4096;  }
}

// ---------------- kernel 1: fused score (chunked max scan + LDS coarse hist) ----------
__global__ __launch_bounds__(256) void score_kernel(
        const float* __restrict__ cls0, const float* __restrict__ cls1,
        const float* __restrict__ cls2,
        const float* __restrict__ ctn0, const float* __restrict__ ctn1,
        const float* __restrict__ ctn2,
        unsigned long long* __restrict__ keys, int* __restrict__ labels,
        int* __restrict__ chist,
        int* __restrict__ cnt, unsigned* __restrict__ flags) {
    __shared__ float pm[5 * SPPB], pv[5 * SPPB];
    __shared__ int pidx[5 * SPPB];
    __shared__ int lch[NCB];                   // block-local coarse hist (block = one level)
    const int tid = threadIdx.x;
    const int base = blockIdx.x * SPPB;
    for (int i = tid; i < NCB; i += 256) lch[i] = 0;
    for (int it = tid; it < 5 * SPPB; it += 256) {
        int c = it / SPPB, pt = it - c * SPPB;
        int g = base + pt, lv, p, HW;
        locate(g, lv, p, HW);
        const float* cls = (lv == 0) ? cls0 : ((lv == 1) ? cls1 : cls2);
        const float* bp = cls + (size_t)c * 16 * HW + p;
        float x[16];
#pragma unroll
        for (int cc = 0; cc < 16; cc++) x[cc] = bp[(size_t)cc * HW];   // independent loads (MLP)
        float m = -INFINITY, v = -INFINITY; int idx = 0;
#pragma unroll
        for (int cc = 0; cc < 16; cc++)
            if (x[cc] > m) { v = m; m = x[cc]; idx = c * 16 + cc; }    // first-occurrence
        pm[it] = m; pv[it] = v; pidx[it] = idx;
    }
    __syncthreads();
    if (tid < SPPB) {
        int g = base + tid, lv, p, HW;
        locate(g, lv, p, HW);
        const float* ctn = (lv == 0) ? ctn0 : ((lv == 1) ? ctn1 : ctn2);
        float m = -INFINITY, v = -INFINITY; int idx = 0;
#pragma unroll
        for (int k = 0; k < 5; k++) {
            float bm = pm[k * SPPB + tid];
            float bv = pv[k * SPPB + tid];
            int bidx = pidx[k * SPPB + tid];
            if (bm > m) { v = fmaxf(m, bv); m = bm; idx = bidx; }
        }
        // joint = sqrt(sig(cls)*sig(ctn)) weakly monotone in cls -> max joint = joint(m)
        float sc = sig_f32_stepwise(ctn[p]);
        float sM = sig_f32_stepwise(m);
        float jm = __fsqrt_rn(sM * sc);
        float sV = sig_f32_stepwise(v);
        float jv = __fsqrt_rn(sV * sc);
        if (jv == jm) {                        // earlier-index label tie possible
            int f = atomicAdd(&cnt[13], 1);
            if (f < FCAP) flags[f] = (unsigned)g;
        }
        unsigned int bits = __float_as_uint(jm);
        keys[g] = ((unsigned long long)bits << 32) | (0xFFFFFFFFu - (unsigned)g);
        labels[g] = idx;
        atomicAdd(&lch[(int)(bits >> 20)], 1);                // coarse -> LDS
    }
    __syncthreads();
    // flush aggregated coarse bins: <=1 global atomic per bin per block
    int lv0, p0, HW0; locate(base, lv0, p0, HW0);             // whole block is in level lv0
    for (int i = tid; i < NCB; i += 256) {
        int v = lch[i];
        if (v) atomicAdd(&chist[lv0 * NCB + i], v);
    }
}

// ---------------- kernel 2: parallel classify scan v2 (84 blocks, block-aggregated) ----
// LDS-buffer the block's kept keys (cb>=chunk, ~55/block), ONE global atomicAdd per
// block per counter (84 total), coalesced flush. Fine hist (cb==chunk only) stays
// scattered-global (256 bins, low contention).
__global__ __launch_bounds__(1024) void scan_kernel(
        const unsigned long long* __restrict__ keys,
        const int* __restrict__ chist,
        int* __restrict__ cnt, int* __restrict__ fineg,
        unsigned long long* __restrict__ comb) {
    const int bid = blockIdx.x, tid = threadIdx.x;
    const int lane = tid & 63, wv = tid >> 6;
    const unsigned long long lmlt = (1ULL << lane) - 1;
    int lv, off;
    if (bid < 64)      { lv = 0; off = bid << 10; }
    else if (bid < 80) { lv = 1; off = (bid - 64) << 10; }
    else               { lv = 2; off = (bid - 80) << 10; }
    const int base = (lv == 0) ? 0 : ((lv == 1) ? 65536 : 81920);

    __shared__ int wtot[16], wsuf[16];
    __shared__ int s_chunk;
    __shared__ int lcnt, labove, lbase;
    __shared__ unsigned long long buf[1024];   // worst-case a whole block is kept

    if (tid == 0) { lcnt = 0; labove = 0; }
    // issue my key load early; it resolves under the chist scan
    unsigned long long key = keys[base + off + tid];

    // coarse suffix scan (shuffle-based) -> chunk
    {
        int s = chist[lv * NCB + tid];
#pragma unroll
        for (int o = 1; o <= 32; o <<= 1) {
            int t = __shfl_down(s, o, 64);
            if (lane + o < 64) s += t;
        }
        if (lane == 0) wtot[wv] = s;
        __syncthreads();
        if (tid < 16) {
            int t = wtot[tid];
#pragma unroll
            for (int o = 1; o <= 8; o <<= 1) {
                int q = __shfl_down(t, o, 64);
                if (tid + o < 16) t += q;
            }
            wsuf[tid] = t;
        }
        __syncthreads();
        int offW = (wv < 15) ? wsuf[wv + 1] : 0;
        int part_i = s + offW;
        int s1 = __shfl_down(s, 1, 64);
        int part_n = (lane < 63) ? (s1 + offW) : offW;
        if (part_i >= K_TOP && part_n < K_TOP) s_chunk = tid;
    }
    __syncthreads();
    const int chunk = s_chunk;

    int cb = (int)(key >> 52);                 // coarse bin (f32 bits >> 20)
    bool keep = cb >= chunk;
    unsigned long long mK = __ballot(keep);
    if (mK) {
        int ldr = __ffsll((long long)mK) - 1;
        int bk;
        if (lane == ldr) bk = atomicAdd(&lcnt, __popcll(mK));   // LDS atomic (cheap)
        bk = __shfl(bk, ldr, 64);
        if (keep) buf[bk + __popcll(mK & lmlt)] = key;
    }
    unsigned long long mS = __ballot(cb > chunk);
    if (lane == 0 && mS) atomicAdd(&labove, __popcll(mS));      // LDS atomic
    if (cb == chunk)
        atomicAdd(&fineg[lv * 256 + ((int)(key >> 44) & 255)], 1);  // scattered global
    __syncthreads();
    if (tid == 0) {
        lbase = atomicAdd(&cnt[0 + lv], lcnt);                  // 84 global atomics total
        if (labove) atomicAdd(&cnt[3 + lv], labove);
        cnt[6 + lv] = chunk;                    // benign duplicate store (same value)
    }
    __syncthreads();
    if (tid < lcnt) comb[(size_t)lv * 65536 + lbase + tid] = buf[tid];   // coalesced
}

// ---------------- kernel 3: select v2 (blocks 0-2) + tie cleanup (block 3) ----------
// Small-data only: fine suffix scan -> Bf; rescan the combined list (~3.5K keys):
// (cb>chunk || fb>Bf) -> sure, (cb==chunk && fb==Bf) -> cand; rank-sort; concat.
__global__ __launch_bounds__(1024) void select_kernel(
        const float* __restrict__ cls0, const float* __restrict__ cls1,
        const float* __restrict__ cls2,
        const float* __restrict__ ctn0, const float* __restrict__ ctn1,
        const float* __restrict__ ctn2,
        const int* __restrict__ cnt, const int* __restrict__ fineg,
        const unsigned long long* __restrict__ comb,
        const unsigned* __restrict__ flags, int* __restrict__ labels,
        unsigned long long* __restrict__ surv) {
    int bid = blockIdx.x, tid = threadIdx.x;
    if (bid == 3) {
        // cleanup: one wave per flagged point, shuffle argmax-reduce (first occurrence)
        int nf = cnt[13]; if (nf > FCAP) nf = FCAP;
        int wave = tid >> 6, lane = tid & 63;
        for (int f = wave; f < nf; f += 16) {
            int g = (int)flags[f], lv, p, HW;
            locate(g, lv, p, HW);
            const float* cls = (lv == 0) ? cls0 : ((lv == 1) ? cls1 : cls2);
            const float* ctn = (lv == 0) ? ctn0 : ((lv == 1) ? ctn1 : ctn2);
            float sc = sig_f32_stepwise(ctn[p]);
            float bestv = -1.0f; int besti = 127;
            {
                float s = sig_f32_stepwise(cls[(size_t)lane * HW + p]);
                float sj = __fsqrt_rn(s * sc);
                bestv = sj; besti = lane;
            }
            if (lane < 16) {
                int c2 = lane + 64;
                float s = sig_f32_stepwise(cls[(size_t)c2 * HW + p]);
                float sj = __fsqrt_rn(s * sc);
                if (sj > bestv) { bestv = sj; besti = c2; }   // tie keeps smaller idx
            }
            for (int off = 32; off; off >>= 1) {
                float ov = __shfl_xor(bestv, off, 64);
                int   oi = __shfl_xor(besti, off, 64);
                if (ov > bestv || (ov == bestv && oi < besti)) { bestv = ov; besti = oi; }
            }
            if (lane == 0) labels[g] = besti;
        }
        return;
    }
    const int lv = bid;
    const int lane = tid & 63, wv = tid >> 6;
    const unsigned long long lmlt = (1ULL << lane) - 1;
    __shared__ int wtot[16], wsuf[16];
    __shared__ int sBf, sSure, sCand;
    __shared__ unsigned long long sel[1024];    // sure keys, rank-sorted in place
    __shared__ unsigned long long cbuf[1024];   // cand keys (bin==Bf), clamped

    const int n     = cnt[0 + lv];              // combined (cb>=chunk) count
    const int above = cnt[3 + lv];              // # keys with cb > chunk (<= 999)
    const int chunk = cnt[6 + lv];
    if (tid == 0) { sSure = 0; sCand = 0; }

    // fine suffix scan (shuffle-based, 4 waves) -> Bf
    {
        int fs = (tid < 256) ? fineg[lv * 256 + tid] : 0;
#pragma unroll
        for (int o = 1; o <= 32; o <<= 1) {
            int t = __shfl_down(fs, o, 64);
            if (lane + o < 64) fs += t;
        }
        if (tid < 256 && lane == 0) wtot[wv] = fs;   // wv in 0..3
        __syncthreads();
        if (tid < 4) {
            int t = wtot[tid];
#pragma unroll
            for (int o = 1; o <= 2; o <<= 1) {
                int q = __shfl_down(t, o, 64);
                if (tid + o < 4) t += q;
            }
            wsuf[tid] = t;
        }
        __syncthreads();
        if (tid < 256) {
            int offW = (wv < 3) ? wsuf[wv + 1] : 0;
            int ge = above + fs + offW;
            int fs1 = __shfl_down(fs, 1, 64);
            int genxt = above + ((lane < 63) ? (fs1 + offW) : offW);
            if (ge >= K_TOP && genxt < K_TOP) sBf = tid;
        }
    }
    __syncthreads();
    const int Bf = sBf;

    // combined-list re-scan (~n/1024 sweeps, n ~ 3.5K)
    for (int i0 = tid; ; i0 += 1024) {
        bool any = (i0 - tid) < n;              // uniform per sweep
        if (!any) break;
        bool valid = i0 < n;
        unsigned long long key = valid ? comb[(size_t)lv * 65536 + i0] : 0ULL;
        int cb = (int)(key >> 52);
        int fb = (int)(key >> 44) & 255;
        bool pS = valid && (cb > chunk || fb > Bf);
        bool pC = valid && (cb == chunk && fb == Bf);
        unsigned long long mS = __ballot(pS);
        if (mS) {
            int ldr = __ffsll((long long)mS) - 1;
            int bk;
            if (lane == ldr) bk = atomicAdd(&sSure, __popcll(mS));
            bk = __shfl(bk, ldr, 64);
            if (pS) sel[bk + __popcll(mS & lmlt)] = key;   // total == Ca <= 999
        }
        unsigned long long mC = __ballot(pC);
        if (mC) {
            int ldr = __ffsll((long long)mC) - 1;
            int bk;
            if (lane == ldr) bk = atomicAdd(&sCand, __popcll(mC));
            bk = __shfl(bk, ldr, 64);
            if (pC) {
                int pos = bk + __popcll(mC & lmlt);
                if (pos < 1024) cbuf[pos] = key;           // clamp (realistic ~tens)
            }
        }
    }
    __syncthreads();

    // O(n) rank-sort (LDS broadcast reads, unique keys), 4-acc ILP, then concat
    const int nS = sSure;                       // == Ca <= 999
    int nC = sCand; if (nC > 1024) nC = 1024;
    unsigned long long myS = (tid < nS) ? sel[tid] : 0ULL;
    unsigned long long myC = (tid < nC) ? cbuf[tid] : 0ULL;
    int a0 = 0, a1 = 0, a2 = 0, a3 = 0;
    int i = 0;
    for (; i + 4 <= nS; i += 4) {
        a0 += (sel[i] > myS); a1 += (sel[i + 1] > myS);
        a2 += (sel[i + 2] > myS); a3 += (sel[i + 3] > myS);
    }
    for (; i < nS; i++) a0 += (sel[i] > myS);
    int rS = a0 + a1 + a2 + a3;
    int b0 = 0, b1 = 0, b2 = 0, b3 = 0;
    i = 0;
    for (; i + 4 <= nC; i += 4) {
        b0 += (cbuf[i] > myC); b1 += (cbuf[i + 1] > myC);
        b2 += (cbuf[i + 2] > myC); b3 += (cbuf[i + 3] > myC);
    }
    for (; i < nC; i++) b0 += (cbuf[i] > myC);
    int rC = b0 + b1 + b2 + b3;
    __syncthreads();                             // all reads done
    if (tid < nS) sel[rS] = myS;
    if (tid < nC) cbuf[rC] = myC;
    __syncthreads();
    // sure keys strictly > cand keys (higher fine/coarse bin) -> concat fully sorted
    if (tid < K_TOP) surv[lv * K_TOP + tid] = (tid < nS) ? sel[tid] : cbuf[tid - nS];
}

// ---------------- kernel 4: 3-way merge by ranking + emit ----------------
__global__ __launch_bounds__(1024) void merge_emit_kernel(
        const unsigned long long* __restrict__ surv,
        const int* __restrict__ labels,
        const float* __restrict__ reg0, const float* __restrict__ reg1,
        const float* __restrict__ reg2,
        const float* __restrict__ scales,
        float* __restrict__ out) {
    __shared__ unsigned long long L[3][1024];
    __shared__ unsigned long long s[NOUT];
    int tid = threadIdx.x;
#pragma unroll
    for (int lv = 0; lv < 3; lv++)
        L[lv][tid] = (tid < K_TOP) ? surv[lv * K_TOP + tid] : 0ULL;
    __syncthreads();
    for (int e = tid; e < NOUT; e += 1024) {
        int a = e / K_TOP, i = e - a * K_TOP;
        unsigned long long key = L[a][i];
        int rank = i;
#pragma unroll
        for (int b = 0; b < 3; b++) {
            if (b == a) continue;
            int lo = 0, hi = K_TOP;
            while (lo < hi) {
                int mid = (lo + hi) >> 1;
                if (L[b][mid] > key) lo = mid + 1; else hi = mid;
            }
            rank += lo;
        }
        s[rank] = key;    // keys unique -> bijective
    }
    __syncthreads();
    for (int r = tid; r < NOUT; r += 1024) {
        unsigned long long key = s[r];
        unsigned int bits = (unsigned)(key >> 32);
        float score = __uint_as_float(bits);
        unsigned int g = 0xFFFFFFFFu - (unsigned)(key & 0xFFFFFFFFULL);
        int lv, p;
        if (g < 65536u)      { lv = 0; p = (int)g; }
        else if (g < 81920u) { lv = 1; p = (int)g - 65536; }
        else                 { lv = 2; p = (int)g - 81920; }
        const float* rp = (lv == 0) ? reg0 : ((lv == 1) ? reg1 : reg2);
        int HW = (lv == 0) ? 65536 : ((lv == 1) ? 16384 : 4096);
        int W = 256 >> lv;
        float strideF = (float)(8 << lv);
        float scale = scales[lv];
        int x = p & (W - 1);
        int y = p >> (8 - lv);
        float r0 = fmaxf(0.0f, rp[0 * HW + p] * scale) * strideF;
        float r1 = fmaxf(0.0f, rp[1 * HW + p] * scale) * strideF;
        float r2 = fmaxf(0.0f, rp[2 * HW + p] * scale) * strideF;
        float r3 = fmaxf(0.0f, rp[3 * HW + p] * scale) * strideF;
        float ax = ((float)x + 0.5f) * strideF;
        float ay = ((float)y + 0.5f) * strideF;
        out[r * 4 + 0] = ax - r0;
        out[r * 4 + 1] = ay - r1;
        out[r * 4 + 2] = ax + r2;
        out[r * 4 + 3] = ay + r3;
        out[12000 + r] = score;
        out[15000 + r] = (float)labels[g];
    }
}

// ---------------- kernel 5: tiled sparse edge extraction (SoA LDS) ----------------
__global__ __launch_bounds__(256) void edge_kernel(const float* __restrict__ out,
                                                   unsigned* __restrict__ edges_g,
                                                   int* __restrict__ cnt) {
    __shared__ float x1[128], y1[128], x2[128], y2[128];
    int t = blockIdx.x, tid = threadIdx.x;
    int ta = 0, rem = t;
    while (rem >= NTILE - ta) { rem -= NTILE - ta; ta++; }
    int tb = ta + rem;                         // ta <= tb
    if (tid < 64) {
        int gi = ta * 64 + tid;
        if (gi < NOUT) {
            float4 b = ((const float4*)out)[gi];
            x1[tid] = b.x; y1[tid] = b.y; x2[tid] = b.z; y2[tid] = b.w;
        }
    } else if (tid < 128) {
        int gj = tb * 64 + (tid - 64);
        if (gj < NOUT) {
            float4 b = ((const float4*)out)[gj];
            x1[tid] = b.x; y1[tid] = b.y; x2[tid] = b.z; y2[tid] = b.w;
        }
    }
    __syncthreads();
#pragma unroll
    for (int q = 0; q < 16; q++) {
        int idx = q * 256 + tid;
        int ii = idx >> 6, jj = idx & 63;
        int i = ta * 64 + ii, j = tb * 64 + jj;
        if (i < j && j < NOUT) {
            float ai = (x2[ii] - x1[ii]) * (y2[ii] - y1[ii]);
            float aj = (x2[64 + jj] - x1[64 + jj]) * (y2[64 + jj] - y1[64 + jj]);
            float xx1 = fmaxf(x1[ii], x1[64 + jj]), yy1 = fmaxf(y1[ii], y1[64 + jj]);
            float xx2 = fminf(x2[ii], x2[64 + jj]), yy2 = fminf(y2[ii], y2[64 + jj]);
            float ww = fmaxf(1e-10f, xx2 - xx1);
            float hh = fmaxf(1e-10f, yy2 - yy1);
            float inter = ww * hh;
            float iou = inter / (((ai + aj) - inter) + 1e-14f);
            if ((double)iou > 0.6) {
                int e = atomicAdd(&cnt[12], 1);
                if (e < ECAP) edges_g[e] = ((unsigned)i << 12) | (unsigned)j;
            }
        }
    }
}

// ---------------- kernel 6: sparse sequential NMS (single block) ----------------
__global__ __launch_bounds__(1024) void nms_sparse_kernel(
        const unsigned* __restrict__ edges_g,
        const int* __restrict__ cnt,
        const float* __restrict__ scores_s,
        float* __restrict__ keep_out) {
    __shared__ unsigned ed[ECAP];
    __shared__ unsigned long long supLds[NWORDS];
    int tid = threadIdx.x;
    int E = cnt[12]; if (E > ECAP) E = ECAP;
    int m = 1; while (m < E) m <<= 1;
    for (int t = tid; t < m; t += 1024) ed[t] = (t < E) ? edges_g[t] : 0xFFFFFFFFu;
    __syncthreads();
    for (int k = 2; k <= m; k <<= 1)
        for (int j = k >> 1; j > 0; j >>= 1) {
            for (int t = tid; t < m; t += 1024) {
                int l = t ^ j;
                if (l > t) {
                    unsigned a = ed[t], b = ed[l];
                    if (((t & k) == 0) ? (a > b) : (a < b)) { ed[t] = b; ed[l] = a; }
                }
            }
            __syncthreads();
        }
    if (tid < 64) {
        int lane = tid;
        unsigned long long supW = 0ULL;
        int ep = 0;
        for (int c = 0; c < NWORDS; c++) {
            unsigned long long cw = __shfl(supW, c, 64);   // complete: sources < c*64 final
            int hi = (c + 1) * 64;
            while (ep < E) {
                unsigned k = ed[ep];
                int i = (int)(k >> 12);
                if (i >= hi) break;
                int j = (int)(k & 4095);
                if (!((cw >> (i & 63)) & 1ULL)) {          // source kept -> suppress target
                    if ((j >> 6) == c) cw |= 1ULL << (j & 63);
                    else if (lane == (j >> 6)) supW |= 1ULL << (j & 63);
                }
                ep++;
            }
            if (lane == c) supW = cw;
        }
        if (lane < NWORDS) supLds[lane] = supW;
    }
    __syncthreads();
    for (int j = tid; j < NOUT; j += 1024) {
        bool s = (supLds[j >> 6] >> (j & 63)) & 1ULL;
        float scv = scores_s[j];
        keep_out[j] = (!s && ((double)scv > 0.05)) ? 1.0f : 0.0f;
    }
}

extern "C" void kernel_launch(void* const* d_in, const int* in_sizes, int n_in,
                              void* d_out, int out_size, void* d_ws, size_t ws_size,
                              hipStream_t stream) {
    const float* cls0 = (const float*)d_in[0];
    const float* reg0 = (const float*)d_in[1];
    const float* ctn0 = (const float*)d_in[2];
    const float* cls1 = (const float*)d_in[3];
    const float* reg1 = (const float*)d_in[4];
    const float* ctn1 = (const float*)d_in[5];
    const float* cls2 = (const float*)d_in[6];
    const float* reg2 = (const float*)d_in[7];
    const float* ctn2 = (const float*)d_in[8];
    const float* scales = (const float*)d_in[9];

    char* ws = (char*)d_ws;
    int* chist = (int*)(ws + CH_OFF);
    int* fineg = (int*)(ws + FINE_OFF);
    int* cnt  = (int*)(ws + CNT_OFF);
    unsigned long long* keys = (unsigned long long*)(ws + KEYS_OFF);
    int* labels = (int*)(ws + LAB_OFF);
    unsigned long long* comb = (unsigned long long*)(ws + COMB_OFF);
    unsigned long long* surv = (unsigned long long*)(ws + SURV_OFF);
    unsigned* edges = (unsigned*)(ws + EDGE_OFF);
    unsigned* flags = (unsigned*)(ws + FLAG_OFF);
    float* out = (float*)d_out;

    // tiny memset: coarse hist + fine hist + counters (15.4 KB)
    hipMemsetAsync(ws, 0, MEMSET_BYTES, stream);

    score_kernel<<<NPTS / SPPB, 256, 0, stream>>>(cls0, cls1, cls2, ctn0, ctn1, ctn2,
                                                  keys, labels, chist, cnt, flags);
    scan_kernel<<<84, 1024, 0, stream>>>(keys, chist, cnt, fineg, comb);
    select_kernel<<<4, 1024, 0, stream>>>(cls0, cls1, cls2, ctn0, ctn1, ctn2,
                                          cnt, fineg, comb, flags, labels, surv);
    merge_emit_kernel<<<1, 1024, 0, stream>>>(surv, labels, reg0, reg1, reg2, scales, out);
    edge_kernel<<<NTILE * (NTILE + 1) / 2, 256, 0, stream>>>(out, edges, cnt);
    nms_sparse_kernel<<<1, 1024, 0, stream>>>(edges, cnt, out + 12000, out + 18000);
}

// Round 11
// 164.147 us; speedup vs baseline: 1.3028x; 1.0270x over previous
//
#include <hip/hip_runtime.h>
#include <cmath>
#include <stdint.h>

#define NPTS   86016
#define NCB    1024          // coarse bins per level (f32 score bits >> 20)
#define K_TOP  1000
#define NOUT   3000
#define NWORDS 47            // ceil(3000/64)
#define NTILE  47
#define ECAP   8192
#define FCAP   1024

// ---- workspace layout (bytes): chist + fine hist + cnt contiguous (one tiny memset) ----
#define CH_OFF     0
#define FINE_OFF   (NCB * 3 * 4)                // 12,288 : 3 x 256 fine bins
#define CNT_OFF    (FINE_OFF + 3 * 256 * 4)     // 15,360
// cnt[0..2]=comb_cnt [3..5]=above_cnt [6..8]=chunk [12]=edge_cnt [13]=flag_cnt
#define MEMSET_BYTES (CNT_OFF + 64)             // 15,424 total
#define KEYS_OFF   (CNT_OFF + 64)
#define LAB_OFF    (KEYS_OFF + NPTS * 8)
#define COMB_OFF   (LAB_OFF + NPTS * 4)         // 3 x 65536 combined (cb>=chunk) keys
#define SURV_OFF   (COMB_OFF + 3 * 65536 * 8)
#define EDGE_OFF   (SURV_OFF + NOUT * 8 + 64)
#define FLAG_OFF   (EDGE_OFF + ECAP * 4)

// stepwise-f32 sigmoid: CR f32 exp, then IEEE f32 add + div (matches numpy per-op chain)
__device__ __forceinline__ float sig_f32_stepwise(float x) {
    float e = (float)exp(-(double)x);   // correctly-rounded f32 exp(-x)
    return 1.0f / (1.0f + e);           // f32 add (CR), f32 div (CR)
}

__device__ __forceinline__ void locate(int g, int& lv, int& p, int& HW) {
    if (g < 65536)      { lv = 0; p = g;         HW = 65536; }
    else if (g < 81920) { lv = 1; p = g - 65536; HW = 16384; }
    else                { lv = 2; p = g - 81920; HW = 4096;  }
}

// ---------------- kernel 1: score v2 (float4 point-vectorized, thread-owns-point) ------
// 336 blocks x 64 threads x 4 points. 1KB/wave-load (was 256B scalar). Flat 80-channel
// scan per point == old chunk+combine (strict-> update, increasing channel order ->
// identical m, v, idx, tie-flag set). Block fully inside one level (boundaries at
// block 256/320) -> per-level LDS coarse-hist flush preserved.
__global__ __launch_bounds__(64) void score_kernel(
        const float* __restrict__ cls0, const float* __restrict__ cls1,
        const float* __restrict__ cls2,
        const float* __restrict__ ctn0, const float* __restrict__ ctn1,
        const float* __restrict__ ctn2,
        unsigned long long* __restrict__ keys, int* __restrict__ labels,
        int* __restrict__ chist,
        int* __restrict__ cnt, unsigned* __restrict__ flags) {
    __shared__ int lch[NCB];                   // block-local coarse hist (block = one level)
    const int tid = threadIdx.x;
    const int bid = blockIdx.x;
    int lv, off;
    if (bid < 256)      { lv = 0; off = bid << 8; }
    else if (bid < 320) { lv = 1; off = (bid - 256) << 8; }
    else                { lv = 2; off = (bid - 320) << 8; }
    const int HW    = (lv == 0) ? 65536 : ((lv == 1) ? 16384 : 4096);
    const int gbase = (lv == 0) ? 0 : ((lv == 1) ? 65536 : 81920);
    const float* cls = (lv == 0) ? cls0 : ((lv == 1) ? cls1 : cls2);
    const float* ctn = (lv == 0) ? ctn0 : ((lv == 1) ? ctn1 : ctn2);

    for (int i = tid; i < NCB; i += 64) lch[i] = 0;
    __syncthreads();

    const int p = off + (tid << 2);            // 4 consecutive points, 16B-aligned
    float m[4], v[4]; int ix[4];
#pragma unroll
    for (int j = 0; j < 4; j++) { m[j] = -INFINITY; v[j] = -INFINITY; ix[j] = 0; }

#pragma unroll 8
    for (int cc = 0; cc < 80; cc++) {
        float4 x4 = *(const float4*)(cls + (size_t)cc * HW + p);
        float xs[4] = { x4.x, x4.y, x4.z, x4.w };
#pragma unroll
        for (int j = 0; j < 4; j++)
            if (xs[j] > m[j]) { v[j] = m[j]; m[j] = xs[j]; ix[j] = cc; }   // first-occurrence
    }

    float4 ct4 = *(const float4*)(ctn + p);
    float cts[4] = { ct4.x, ct4.y, ct4.z, ct4.w };
#pragma unroll
    for (int j = 0; j < 4; j++) {
        int g = gbase + p + j;
        // joint = sqrt(sig(cls)*sig(ctn)) weakly monotone in cls -> max joint = joint(m)
        float sc = sig_f32_stepwise(cts[j]);
        float jm = __fsqrt_rn(sig_f32_stepwise(m[j]) * sc);
        float jv = __fsqrt_rn(sig_f32_stepwise(v[j]) * sc);
        if (jv == jm) {                        // earlier-index label tie possible
            int f = atomicAdd(&cnt[13], 1);
            if (f < FCAP) flags[f] = (unsigned)g;
        }
        unsigned int bits = __float_as_uint(jm);
        keys[g] = ((unsigned long long)bits << 32) | (0xFFFFFFFFu - (unsigned)g);
        labels[g] = ix[j];
        atomicAdd(&lch[(int)(bits >> 20)], 1);                // coarse -> LDS
    }
    __syncthreads();
    // flush aggregated coarse bins: <=1 global atomic per bin per block
    for (int i = tid; i < NCB; i += 64) {
        int vv = lch[i];
        if (vv) atomicAdd(&chist[lv * NCB + i], vv);
    }
}

// ---------------- kernel 2: parallel classify scan v2 (84 blocks, block-aggregated) ----
// LDS-buffer the block's kept keys (cb>=chunk, ~55/block), ONE global atomicAdd per
// block per counter (84 total), coalesced flush. Fine hist (cb==chunk only) stays
// scattered-global (256 bins, low contention).
__global__ __launch_bounds__(1024) void scan_kernel(
        const unsigned long long* __restrict__ keys,
        const int* __restrict__ chist,
        int* __restrict__ cnt, int* __restrict__ fineg,
        unsigned long long* __restrict__ comb) {
    const int bid = blockIdx.x, tid = threadIdx.x;
    const int lane = tid & 63, wv = tid >> 6;
    const unsigned long long lmlt = (1ULL << lane) - 1;
    int lv, off;
    if (bid < 64)      { lv = 0; off = bid << 10; }
    else if (bid < 80) { lv = 1; off = (bid - 64) << 10; }
    else               { lv = 2; off = (bid - 80) << 10; }
    const int base = (lv == 0) ? 0 : ((lv == 1) ? 65536 : 81920);

    __shared__ int wtot[16], wsuf[16];
    __shared__ int s_chunk;
    __shared__ int lcnt, labove, lbase;
    __shared__ unsigned long long buf[1024];   // worst-case a whole block is kept

    if (tid == 0) { lcnt = 0; labove = 0; }
    // issue my key load early; it resolves under the chist scan
    unsigned long long key = keys[base + off + tid];

    // coarse suffix scan (shuffle-based) -> chunk
    {
        int s = chist[lv * NCB + tid];
#pragma unroll
        for (int o = 1; o <= 32; o <<= 1) {
            int t = __shfl_down(s, o, 64);
            if (lane + o < 64) s += t;
        }
        if (lane == 0) wtot[wv] = s;
        __syncthreads();
        if (tid < 16) {
            int t = wtot[tid];
#pragma unroll
            for (int o = 1; o <= 8; o <<= 1) {
                int q = __shfl_down(t, o, 64);
                if (tid + o < 16) t += q;
            }
            wsuf[tid] = t;
        }
        __syncthreads();
        int offW = (wv < 15) ? wsuf[wv + 1] : 0;
        int part_i = s + offW;
        int s1 = __shfl_down(s, 1, 64);
        int part_n = (lane < 63) ? (s1 + offW) : offW;
        if (part_i >= K_TOP && part_n < K_TOP) s_chunk = tid;
    }
    __syncthreads();
    const int chunk = s_chunk;

    int cb = (int)(key >> 52);                 // coarse bin (f32 bits >> 20)
    bool keep = cb >= chunk;
    unsigned long long mK = __ballot(keep);
    if (mK) {
        int ldr = __ffsll((long long)mK) - 1;
        int bk;
        if (lane == ldr) bk = atomicAdd(&lcnt, __popcll(mK));   // LDS atomic (cheap)
        bk = __shfl(bk, ldr, 64);
        if (keep) buf[bk + __popcll(mK & lmlt)] = key;
    }
    unsigned long long mS = __ballot(cb > chunk);
    if (lane == 0 && mS) atomicAdd(&labove, __popcll(mS));      // LDS atomic
    if (cb == chunk)
        atomicAdd(&fineg[lv * 256 + ((int)(key >> 44) & 255)], 1);  // scattered global
    __syncthreads();
    if (tid == 0) {
        lbase = atomicAdd(&cnt[0 + lv], lcnt);                  // 84 global atomics total
        if (labove) atomicAdd(&cnt[3 + lv], labove);
        cnt[6 + lv] = chunk;                    // benign duplicate store (same value)
    }
    __syncthreads();
    if (tid < lcnt) comb[(size_t)lv * 65536 + lbase + tid] = buf[tid];   // coalesced
}

// ---------------- kernel 3: select v2 (blocks 0-2) + tie cleanup (block 3) ----------
// Small-data only: fine suffix scan -> Bf; rescan the combined list (~3.5K keys):
// (cb>chunk || fb>Bf) -> sure, (cb==chunk && fb==Bf) -> cand; rank-sort; concat.
__global__ __launch_bounds__(1024) void select_kernel(
        const float* __restrict__ cls0, const float* __restrict__ cls1,
        const float* __restrict__ cls2,
        const float* __restrict__ ctn0, const float* __restrict__ ctn1,
        const float* __restrict__ ctn2,
        const int* __restrict__ cnt, const int* __restrict__ fineg,
        const unsigned long long* __restrict__ comb,
        const unsigned* __restrict__ flags, int* __restrict__ labels,
        unsigned long long* __restrict__ surv) {
    int bid = blockIdx.x, tid = threadIdx.x;
    if (bid == 3) {
        // cleanup: one wave per flagged point, shuffle argmax-reduce (first occurrence)
        int nf = cnt[13]; if (nf > FCAP) nf = FCAP;
        int wave = tid >> 6, lane = tid & 63;
        for (int f = wave; f < nf; f += 16) {
            int g = (int)flags[f], lv, p, HW;
            locate(g, lv, p, HW);
            const float* cls = (lv == 0) ? cls0 : ((lv == 1) ? cls1 : cls2);
            const float* ctn = (lv == 0) ? ctn0 : ((lv == 1) ? ctn1 : ctn2);
            float sc = sig_f32_stepwise(ctn[p]);
            float bestv = -1.0f; int besti = 127;
            {
                float s = sig_f32_stepwise(cls[(size_t)lane * HW + p]);
                float sj = __fsqrt_rn(s * sc);
                bestv = sj; besti = lane;
            }
            if (lane < 16) {
                int c2 = lane + 64;
                float s = sig_f32_stepwise(cls[(size_t)c2 * HW + p]);
                float sj = __fsqrt_rn(s * sc);
                if (sj > bestv) { bestv = sj; besti = c2; }   // tie keeps smaller idx
            }
            for (int off = 32; off; off >>= 1) {
                float ov = __shfl_xor(bestv, off, 64);
                int   oi = __shfl_xor(besti, off, 64);
                if (ov > bestv || (ov == bestv && oi < besti)) { bestv = ov; besti = oi; }
            }
            if (lane == 0) labels[g] = besti;
        }
        return;
    }
    const int lv = bid;
    const int lane = tid & 63, wv = tid >> 6;
    const unsigned long long lmlt = (1ULL << lane) - 1;
    __shared__ int wtot[16], wsuf[16];
    __shared__ int sBf, sSure, sCand;
    __shared__ unsigned long long sel[1024];    // sure keys, rank-sorted in place
    __shared__ unsigned long long cbuf[1024];   // cand keys (bin==Bf), clamped

    const int n     = cnt[0 + lv];              // combined (cb>=chunk) count
    const int above = cnt[3 + lv];              // # keys with cb > chunk (<= 999)
    const int chunk = cnt[6 + lv];
    if (tid == 0) { sSure = 0; sCand = 0; }

    // fine suffix scan (shuffle-based, 4 waves) -> Bf
    {
        int fs = (tid < 256) ? fineg[lv * 256 + tid] : 0;
#pragma unroll
        for (int o = 1; o <= 32; o <<= 1) {
            int t = __shfl_down(fs, o, 64);
            if (lane + o < 64) fs += t;
        }
        if (tid < 256 && lane == 0) wtot[wv] = fs;   // wv in 0..3
        __syncthreads();
        if (tid < 4) {
            int t = wtot[tid];
#pragma unroll
            for (int o = 1; o <= 2; o <<= 1) {
                int q = __shfl_down(t, o, 64);
                if (tid + o < 4) t += q;
            }
            wsuf[tid] = t;
        }
        __syncthreads();
        if (tid < 256) {
            int offW = (wv < 3) ? wsuf[wv + 1] : 0;
            int ge = above + fs + offW;
            int fs1 = __shfl_down(fs, 1, 64);
            int genxt = above + ((lane < 63) ? (fs1 + offW) : offW);
            if (ge >= K_TOP && genxt < K_TOP) sBf = tid;
        }
    }
    __syncthreads();
    const int Bf = sBf;

    // combined-list re-scan (~n/1024 sweeps, n ~ 3.5K)
    for (int i0 = tid; ; i0 += 1024) {
        bool any = (i0 - tid) < n;              // uniform per sweep
        if (!any) break;
        bool valid = i0 < n;
        unsigned long long key = valid ? comb[(size_t)lv * 65536 + i0] : 0ULL;
        int cb = (int)(key >> 52);
        int fb = (int)(key >> 44) & 255;
        bool pS = valid && (cb > chunk || fb > Bf);
        bool pC = valid && (cb == chunk && fb == Bf);
        unsigned long long mS = __ballot(pS);
        if (mS) {
            int ldr = __ffsll((long long)mS) - 1;
            int bk;
            if (lane == ldr) bk = atomicAdd(&sSure, __popcll(mS));
            bk = __shfl(bk, ldr, 64);
            if (pS) sel[bk + __popcll(mS & lmlt)] = key;   // total == Ca <= 999
        }
        unsigned long long mC = __ballot(pC);
        if (mC) {
            int ldr = __ffsll((long long)mC) - 1;
            int bk;
            if (lane == ldr) bk = atomicAdd(&sCand, __popcll(mC));
            bk = __shfl(bk, ldr, 64);
            if (pC) {
                int pos = bk + __popcll(mC & lmlt);
                if (pos < 1024) cbuf[pos] = key;           // clamp (realistic ~tens)
            }
        }
    }
    __syncthreads();

    // O(n) rank-sort (LDS broadcast reads, unique keys), 4-acc ILP, then concat
    const int nS = sSure;                       // == Ca <= 999
    int nC = sCand; if (nC > 1024) nC = 1024;
    unsigned long long myS = (tid < nS) ? sel[tid] : 0ULL;
    unsigned long long myC = (tid < nC) ? cbuf[tid] : 0ULL;
    int a0 = 0, a1 = 0, a2 = 0, a3 = 0;
    int i = 0;
    for (; i + 4 <= nS; i += 4) {
        a0 += (sel[i] > myS); a1 += (sel[i + 1] > myS);
        a2 += (sel[i + 2] > myS); a3 += (sel[i + 3] > myS);
    }
    for (; i < nS; i++) a0 += (sel[i] > myS);
    int rS = a0 + a1 + a2 + a3;
    int b0 = 0, b1 = 0, b2 = 0, b3 = 0;
    i = 0;
    for (; i + 4 <= nC; i += 4) {
        b0 += (cbuf[i] > myC); b1 += (cbuf[i + 1] > myC);
        b2 += (cbuf[i + 2] > myC); b3 += (cbuf[i + 3] > myC);
    }
    for (; i < nC; i++) b0 += (cbuf[i] > myC);
    int rC = b0 + b1 + b2 + b3;
    __syncthreads();                             // all reads done
    if (tid < nS) sel[rS] = myS;
    if (tid < nC) cbuf[rC] = myC;
    __syncthreads();
    // sure keys strictly > cand keys (higher fine/coarse bin) -> concat fully sorted
    if (tid < K_TOP) surv[lv * K_TOP + tid] = (tid < nS) ? sel[tid] : cbuf[tid - nS];
}

// ---------------- kernel 4: 3-way merge by ranking + emit ----------------
__global__ __launch_bounds__(1024) void merge_emit_kernel(
        const unsigned long long* __restrict__ surv,
        const int* __restrict__ labels,
        const float* __restrict__ reg0, const float* __restrict__ reg1,
        const float* __restrict__ reg2,
        const float* __restrict__ scales,
        float* __restrict__ out) {
    __shared__ unsigned long long L[3][1024];
    __shared__ unsigned long long s[NOUT];
    int tid = threadIdx.x;
#pragma unroll
    for (int lv = 0; lv < 3; lv++)
        L[lv][tid] = (tid < K_TOP) ? surv[lv * K_TOP + tid] : 0ULL;
    __syncthreads();
    for (int e = tid; e < NOUT; e += 1024) {
        int a = e / K_TOP, i = e - a * K_TOP;
        unsigned long long key = L[a][i];
        int rank = i;
#pragma unroll
        for (int b = 0; b < 3; b++) {
            if (b == a) continue;
            int lo = 0, hi = K_TOP;
            while (lo < hi) {
                int mid = (lo + hi) >> 1;
                if (L[b][mid] > key) lo = mid + 1; else hi = mid;
            }
            rank += lo;
        }
        s[rank] = key;    // keys unique -> bijective
    }
    __syncthreads();
    for (int r = tid; r < NOUT; r += 1024) {
        unsigned long long key = s[r];
        unsigned int bits = (unsigned)(key >> 32);
        float score = __uint_as_float(bits);
        unsigned int g = 0xFFFFFFFFu - (unsigned)(key & 0xFFFFFFFFULL);
        int lv, p;
        if (g < 65536u)      { lv = 0; p = (int)g; }
        else if (g < 81920u) { lv = 1; p = (int)g - 65536; }
        else                 { lv = 2; p = (int)g - 81920; }
        const float* rp = (lv == 0) ? reg0 : ((lv == 1) ? reg1 : reg2);
        int HW = (lv == 0) ? 65536 : ((lv == 1) ? 16384 : 4096);
        int W = 256 >> lv;
        float strideF = (float)(8 << lv);
        float scale = scales[lv];
        int x = p & (W - 1);
        int y = p >> (8 - lv);
        float r0 = fmaxf(0.0f, rp[0 * HW + p] * scale) * strideF;
        float r1 = fmaxf(0.0f, rp[1 * HW + p] * scale) * strideF;
        float r2 = fmaxf(0.0f, rp[2 * HW + p] * scale) * strideF;
        float r3 = fmaxf(0.0f, rp[3 * HW + p] * scale) * strideF;
        float ax = ((float)x + 0.5f) * strideF;
        float ay = ((float)y + 0.5f) * strideF;
        out[r * 4 + 0] = ax - r0;
        out[r * 4 + 1] = ay - r1;
        out[r * 4 + 2] = ax + r2;
        out[r * 4 + 3] = ay + r3;
        out[12000 + r] = score;
        out[15000 + r] = (float)labels[g];
    }
}

// ---------------- kernel 5: tiled sparse edge extraction (SoA LDS) ----------------
__global__ __launch_bounds__(256) void edge_kernel(const float* __restrict__ out,
                                                   unsigned* __restrict__ edges_g,
                                                   int* __restrict__ cnt) {
    __shared__ float x1[128], y1[128], x2[128], y2[128];
    int t = blockIdx.x, tid = threadIdx.x;
    int ta = 0, rem = t;
    while (rem >= NTILE - ta) { rem -= NTILE - ta; ta++; }
    int tb = ta + rem;                         // ta <= tb
    if (tid < 64) {
        int gi = ta * 64 + tid;
        if (gi < NOUT) {
            float4 b = ((const float4*)out)[gi];
            x1[tid] = b.x; y1[tid] = b.y; x2[tid] = b.z; y2[tid] = b.w;
        }
    } else if (tid < 128) {
        int gj = tb * 64 + (tid - 64);
        if (gj < NOUT) {
            float4 b = ((const float4*)out)[gj];
            x1[tid] = b.x; y1[tid] = b.y; x2[tid] = b.z; y2[tid] = b.w;
        }
    }
    __syncthreads();
#pragma unroll
    for (int q = 0; q < 16; q++) {
        int idx = q * 256 + tid;
        int ii = idx >> 6, jj = idx & 63;
        int i = ta * 64 + ii, j = tb * 64 + jj;
        if (i < j && j < NOUT) {
            float ai = (x2[ii] - x1[ii]) * (y2[ii] - y1[ii]);
            float aj = (x2[64 + jj] - x1[64 + jj]) * (y2[64 + jj] - y1[64 + jj]);
            float xx1 = fmaxf(x1[ii], x1[64 + jj]), yy1 = fmaxf(y1[ii], y1[64 + jj]);
            float xx2 = fminf(x2[ii], x2[64 + jj]), yy2 = fminf(y2[ii], y2[64 + jj]);
            float ww = fmaxf(1e-10f, xx2 - xx1);
            float hh = fmaxf(1e-10f, yy2 - yy1);
            float inter = ww * hh;
            float iou = inter / (((ai + aj) - inter) + 1e-14f);
            if ((double)iou > 0.6) {
                int e = atomicAdd(&cnt[12], 1);
                if (e < ECAP) edges_g[e] = ((unsigned)i << 12) | (unsigned)j;
            }
        }
    }
}

// ---------------- kernel 6: sparse sequential NMS (single block) ----------------
__global__ __launch_bounds__(1024) void nms_sparse_kernel(
        const unsigned* __restrict__ edges_g,
        const int* __restrict__ cnt,
        const float* __restrict__ scores_s,
        float* __restrict__ keep_out) {
    __shared__ unsigned ed[ECAP];
    __shared__ unsigned long long supLds[NWORDS];
    int tid = threadIdx.x;
    int E = cnt[12]; if (E > ECAP) E = ECAP;
    int m = 1; while (m < E) m <<= 1;
    for (int t = tid; t < m; t += 1024) ed[t] = (t < E) ? edges_g[t] : 0xFFFFFFFFu;
    __syncthreads();
    for (int k = 2; k <= m; k <<= 1)
        for (int j = k >> 1; j > 0; j >>= 1) {
            for (int t = tid; t < m; t += 1024) {
                int l = t ^ j;
                if (l > t) {
                    unsigned a = ed[t], b = ed[l];
                    if (((t & k) == 0) ? (a > b) : (a < b)) { ed[t] = b; ed[l] = a; }
                }
            }
            __syncthreads();
        }
    if (tid < 64) {
        int lane = tid;
        unsigned long long supW = 0ULL;
        int ep = 0;
        for (int c = 0; c < NWORDS; c++) {
            unsigned long long cw = __shfl(supW, c, 64);   // complete: sources < c*64 final
            int hi = (c + 1) * 64;
            while (ep < E) {
                unsigned k = ed[ep];
                int i = (int)(k >> 12);
                if (i >= hi) break;
                int j = (int)(k & 4095);
                if (!((cw >> (i & 63)) & 1ULL)) {          // source kept -> suppress target
                    if ((j >> 6) == c) cw |= 1ULL << (j & 63);
                    else if (lane == (j >> 6)) supW |= 1ULL << (j & 63);
                }
                ep++;
            }
            if (lane == c) supW = cw;
        }
        if (lane < NWORDS) supLds[lane] = supW;
    }
    __syncthreads();
    for (int j = tid; j < NOUT; j += 1024) {
        bool s = (supLds[j >> 6] >> (j & 63)) & 1ULL;
        float scv = scores_s[j];
        keep_out[j] = (!s && ((double)scv > 0.05)) ? 1.0f : 0.0f;
    }
}

extern "C" void kernel_launch(void* const* d_in, const int* in_sizes, int n_in,
                              void* d_out, int out_size, void* d_ws, size_t ws_size,
                              hipStream_t stream) {
    const float* cls0 = (const float*)d_in[0];
    const float* reg0 = (const float*)d_in[1];
    const float* ctn0 = (const float*)d_in[2];
    const float* cls1 = (const float*)d_in[3];
    const float* reg1 = (const float*)d_in[4];
    const float* ctn1 = (const float*)d_in[5];
    const float* cls2 = (const float*)d_in[6];
    const float* reg2 = (const float*)d_in[7];
    const float* ctn2 = (const float*)d_in[8];
    const float* scales = (const float*)d_in[9];

    char* ws = (char*)d_ws;
    int* chist = (int*)(ws + CH_OFF);
    int* fineg = (int*)(ws + FINE_OFF);
    int* cnt  = (int*)(ws + CNT_OFF);
    unsigned long long* keys = (unsigned long long*)(ws + KEYS_OFF);
    int* labels = (int*)(ws + LAB_OFF);
    unsigned long long* comb = (unsigned long long*)(ws + COMB_OFF);
    unsigned long long* surv = (unsigned long long*)(ws + SURV_OFF);
    unsigned* edges = (unsigned*)(ws + EDGE_OFF);
    unsigned* flags = (unsigned*)(ws + FLAG_OFF);
    float* out = (float*)d_out;

    // tiny memset: coarse hist + fine hist + counters (15.4 KB)
    hipMemsetAsync(ws, 0, MEMSET_BYTES, stream);

    score_kernel<<<336, 64, 0, stream>>>(cls0, cls1, cls2, ctn0, ctn1, ctn2,
                                         keys, labels, chist, cnt, flags);
    scan_kernel<<<84, 1024, 0, stream>>>(keys, chist, cnt, fineg, comb);
    select_kernel<<<4, 1024, 0, stream>>>(cls0, cls1, cls2, ctn0, ctn1, ctn2,
                                          cnt, fineg, comb, flags, labels, surv);
    merge_emit_kernel<<<1, 1024, 0, stream>>>(surv, labels, reg0, reg1, reg2, scales, out);
    edge_kernel<<<NTILE * (NTILE + 1) / 2, 256, 0, stream>>>(out, edges, cnt);
    nms_sparse_kernel<<<1, 1024, 0, stream>>>(edges, cnt, out + 12000, out + 18000);
}